// Round 6
// baseline (418.001 us; speedup 1.0000x reference)
//
#include <hip/hip_runtime.h>

#define HH 448
#define WW 512
#define NPIX (HH * WW)

struct Res { int idx; float ent; };

__device__ __forceinline__ float lrelu(float v) { return v > 0.0f ? v : 0.01f * v; }

__device__ __forceinline__ Res argmax_ent16(const float* __restrict__ v) {
    float m = v[0]; int idx = 0;
#pragma unroll
    for (int i = 1; i < 16; i++) { if (v[i] > m) { m = v[i]; idx = i; } }
    float s = 0.0f, dot = 0.0f;
#pragma unroll
    for (int i = 0; i < 16; i++) {
        float t = __expf(v[i] - m);
        s += t;
        dot = fmaf(t, v[i], dot);
    }
    Res r; r.idx = idx; r.ent = m + __logf(s) - dot / s;
    return r;
}

// NPX pixels, weight layout [in=32][OUT] (stages 2/3). x,y are [NPX*32] (y uses first OUT of each 32-stride).
// Per-pixel fma order identical to the 1-pixel version (bitwise-stable).
template <int NPX, int OUT>
__device__ __forceinline__ void layer_ioN(const float* __restrict__ w,
                                          const float* __restrict__ b,
                                          const float* __restrict__ x,
                                          float* __restrict__ y) {
    float acc[NPX][OUT];
#pragma unroll
    for (int n = 0; n < NPX; n++)
#pragma unroll
        for (int o = 0; o < OUT; o++) acc[n][o] = b[o];
#pragma unroll
    for (int i = 0; i < 32; i++) {
        const float4* row = (const float4*)(w + i * OUT);
#pragma unroll
        for (int q = 0; q < OUT / 4; q++) {
            float4 wv = row[q];
#pragma unroll
            for (int n = 0; n < NPX; n++) {
                float xi = x[n * 32 + i];
                acc[n][4 * q + 0] = fmaf(xi, wv.x, acc[n][4 * q + 0]);
                acc[n][4 * q + 1] = fmaf(xi, wv.y, acc[n][4 * q + 1]);
                acc[n][4 * q + 2] = fmaf(xi, wv.z, acc[n][4 * q + 2]);
                acc[n][4 * q + 3] = fmaf(xi, wv.w, acc[n][4 * q + 3]);
            }
        }
    }
#pragma unroll
    for (int n = 0; n < NPX; n++)
#pragma unroll
        for (int o = 0; o < OUT; o++) y[n * 32 + o] = acc[n][o];
}

// NPX pixels, weight layout [OUT][in=32] (stage 1, per-line uniform weights).
template <int NPX, int OUT>
__device__ __forceinline__ void layer_oiN(const float* __restrict__ w,
                                          const float* __restrict__ b,
                                          const float* __restrict__ x,
                                          float* __restrict__ y) {
#pragma unroll
    for (int o = 0; o < OUT; o++) {
        const float4* row = (const float4*)(w + o * 32);
        float a[NPX];
#pragma unroll
        for (int n = 0; n < NPX; n++) a[n] = b[o];
#pragma unroll
        for (int q = 0; q < 8; q++) {
            float4 wv = row[q];
#pragma unroll
            for (int n = 0; n < NPX; n++) {
                a[n] = fmaf(wv.x, x[n * 32 + 4 * q + 0], a[n]);
                a[n] = fmaf(wv.y, x[n * 32 + 4 * q + 1], a[n]);
                a[n] = fmaf(wv.z, x[n * 32 + 4 * q + 2], a[n]);
                a[n] = fmaf(wv.w, x[n * 32 + 4 * q + 3], a[n]);
            }
        }
#pragma unroll
        for (int n = 0; n < NPX; n++) y[n * 32 + o] = a[n];
    }
}

// NPX-pixel expert MLP 32->32->32->16, shared expert e, per-lane global weights.
template <int NPX>
__device__ __forceinline__ void expert_mlpN(const float* __restrict__ xb,
                                            const int* __restrict__ p,
                                            const float* __restrict__ w0, const float* __restrict__ b0,
                                            const float* __restrict__ w1, const float* __restrict__ b1,
                                            const float* __restrict__ w2, const float* __restrict__ b2,
                                            size_t e, Res* __restrict__ r) {
    float x[NPX * 32], y[NPX * 32];
#pragma unroll
    for (int n = 0; n < NPX; n++)
#pragma unroll
        for (int c = 0; c < 32; c++) x[n * 32 + c] = xb[(size_t)c * NPIX + p[n]];
    layer_ioN<NPX, 32>(w0 + e * 1024, b0 + e * 32, x, y);
#pragma unroll
    for (int k = 0; k < NPX * 32; k++) y[k] = lrelu(y[k]);
    layer_ioN<NPX, 32>(w1 + e * 1024, b1 + e * 32, y, x);
#pragma unroll
    for (int k = 0; k < NPX * 32; k++) x[k] = lrelu(x[k]);
    layer_ioN<NPX, 16>(w2 + e * 512, b2 + e * 16, x, y);
#pragma unroll
    for (int n = 0; n < NPX; n++) r[n] = argmax_ent16(y + n * 32);
}

__global__ __launch_bounds__(128, 2) void cls3_kernel(
    const float* __restrict__ x_in,
    const float* __restrict__ w1_0, const float* __restrict__ b1_0,
    const float* __restrict__ w1_1, const float* __restrict__ b1_1,
    const float* __restrict__ w1_2, const float* __restrict__ b1_2,
    const float* __restrict__ w2_0, const float* __restrict__ b2_0,
    const float* __restrict__ w2_1, const float* __restrict__ b2_1,
    const float* __restrict__ w2_2, const float* __restrict__ b2_2,
    const float* __restrict__ w3_0, const float* __restrict__ b3_0,
    const float* __restrict__ w3_1, const float* __restrict__ b3_1,
    const float* __restrict__ w3_2, const float* __restrict__ b3_2,
    float* __restrict__ out) {
    __shared__ int sCls[256];
    __shared__ int sRaw[256];
    __shared__ int sPerm[256];
    __shared__ int sCnt[192];
    __shared__ int sScan[192];
    __shared__ int sOffs[192];

    const int h = blockIdx.x >> 1;
    const int base = (blockIdx.x & 1) << 8;   // 0 or 256 within the line
    const int t = threadIdx.x;                 // 0..127
    const size_t rowoff = (size_t)h * WW + base;

    // ---- stage 1: 2 pixels/thread (t, t+128), per-line uniform weights ----
    {
        float x[64], y[64];
#pragma unroll
        for (int c = 0; c < 32; c++) {
            x[c] = x_in[(size_t)c * NPIX + rowoff + t];
            x[32 + c] = x_in[(size_t)c * NPIX + rowoff + t + 128];
        }
        layer_oiN<2, 32>(w1_0 + (size_t)h * 1024, b1_0 + (size_t)h * 32, x, y);
#pragma unroll
        for (int k = 0; k < 64; k++) y[k] = lrelu(y[k]);
        layer_oiN<2, 32>(w1_1 + (size_t)h * 1024, b1_1 + (size_t)h * 32, y, x);
#pragma unroll
        for (int k = 0; k < 64; k++) x[k] = lrelu(x[k]);
        layer_oiN<2, 16>(w1_2 + (size_t)h * 512, b1_2 + (size_t)h * 16, x, y);
        Res r0 = argmax_ent16(y);
        Res r1 = argmax_ent16(y + 32);
        out[NPIX + rowoff + t] = r0.ent;          // e1
        out[NPIX + rowoff + t + 128] = r1.ent;
        sCls[t] = r0.idx;
        sCls[t + 128] = r1.idx;
    }
    if (t < 16) sCnt[t] = 0;
    __syncthreads();

    // ---- counting sort by inds1 (16 bins, 256 px, 2 px/thread) ----
    int rkA = atomicAdd(&sCnt[sCls[t]], 1);
    int rkB = atomicAdd(&sCnt[sCls[t + 128]], 1);
    __syncthreads();
    if (t < 16) {
        int v = sCnt[t];
        int incl = v;
#pragma unroll
        for (int d = 1; d < 16; d <<= 1) {
            int n = __shfl_up(incl, d, 64);
            if (t >= d) incl += n;
        }
        sOffs[t] = incl - v;
    }
    __syncthreads();
    sPerm[sOffs[sCls[t]] + rkA] = t;
    sPerm[sOffs[sCls[t + 128]] + rkB] = t + 128;
    __syncthreads();

    // ---- stage 2: paired sorted pixels ----
    {
        int pp[2] = { sPerm[2 * t], sPerm[2 * t + 1] };
        int c0 = sCls[pp[0]], c1 = sCls[pp[1]];
        const float* xb = x_in + (size_t)32 * NPIX + rowoff;
        Res rr[2];
        if (c0 == c1) {
            expert_mlpN<2>(xb, pp, w2_0, b2_0, w2_1, b2_1, w2_2, b2_2,
                           (size_t)h * 16 + c0, rr);
        } else {
            expert_mlpN<1>(xb, pp, w2_0, b2_0, w2_1, b2_1, w2_2, b2_2,
                           (size_t)h * 16 + c0, rr);
            expert_mlpN<1>(xb, pp + 1, w2_0, b2_0, w2_1, b2_1, w2_2, b2_2,
                           (size_t)h * 16 + c1, rr + 1);
        }
#pragma unroll
        for (int n = 0; n < 2; n++) {
            int p = pp[n];
            int c = (n == 0) ? c0 : c1;
            out[2 * NPIX + rowoff + p] = rr[n].ent;   // e2
            int raw = c * 12 + rr[n].idx - 2;
            sRaw[p] = raw;
            int cl = raw < 0 ? 0 : (raw > 191 ? 191 : raw);
            sCls[p] = cl;   // own pixel slots only -> no race
        }
    }
    sCnt[t] = 0;
    if (t < 64) sCnt[128 + t] = 0;
    __syncthreads();

    // ---- counting sort by clipped inds12 (192 bins, 256 px, 2 px/thread) ----
    rkA = atomicAdd(&sCnt[sCls[t]], 1);
    rkB = atomicAdd(&sCnt[sCls[t + 128]], 1);
    __syncthreads();
    {
        int l = t & 63;
        if (t < 64) {
            int v = sCnt[l];
            int incl = v;
#pragma unroll
            for (int d = 1; d < 64; d <<= 1) {
                int n = __shfl_up(incl, d, 64);
                if (l >= d) incl += n;
            }
            sScan[l] = incl;
            int v2 = sCnt[128 + l];
            int incl2 = v2;
#pragma unroll
            for (int d = 1; d < 64; d <<= 1) {
                int n = __shfl_up(incl2, d, 64);
                if (l >= d) incl2 += n;
            }
            sScan[128 + l] = incl2;
        } else {
            int v = sCnt[64 + l];
            int incl = v;
#pragma unroll
            for (int d = 1; d < 64; d <<= 1) {
                int n = __shfl_up(incl, d, 64);
                if (l >= d) incl += n;
            }
            sScan[64 + l] = incl;
        }
    }
    __syncthreads();
    {
        int b0i = t;
        int off = sScan[b0i] - sCnt[b0i];
        if (b0i >= 64) off += sScan[63];
        if (b0i >= 128) off += sScan[127];
        sOffs[b0i] = off;
        if (t < 64) {
            int b1i = 128 + t;
            int off1 = sScan[b1i] - sCnt[b1i] + sScan[63] + sScan[127];
            sOffs[b1i] = off1;
        }
    }
    __syncthreads();
    sPerm[sOffs[sCls[t]] + rkA] = t;
    sPerm[sOffs[sCls[t + 128]] + rkB] = t + 128;
    __syncthreads();

    // ---- stage 3: paired sorted pixels ----
    {
        int pp[2] = { sPerm[2 * t], sPerm[2 * t + 1] };
        int cl0 = sCls[pp[0]], cl1 = sCls[pp[1]];
        const float* xb = x_in + (size_t)64 * NPIX + rowoff;
        Res rr[2];
        if (cl0 == cl1) {
            expert_mlpN<2>(xb, pp, w3_0, b3_0, w3_1, b3_1, w3_2, b3_2,
                           (size_t)h * 192 + cl0, rr);
        } else {
            expert_mlpN<1>(xb, pp, w3_0, b3_0, w3_1, b3_1, w3_2, b3_2,
                           (size_t)h * 192 + cl0, rr);
            expert_mlpN<1>(xb, pp + 1, w3_0, b3_0, w3_1, b3_1, w3_2, b3_2,
                           (size_t)h * 192 + cl1, rr + 1);
        }
#pragma unroll
        for (int n = 0; n < 2; n++) {
            int p = pp[n];
            int raw = sRaw[p];
            out[3 * NPIX + rowoff + p] = rr[n].ent;   // e3
            int i123 = raw * 8 + rr[n].idx - 4;
            i123 = i123 < 0 ? 0 : (i123 > 1535 ? 1535 : i123);
            out[rowoff + p] = (float)i123;            // inds123 as float
        }
    }
}

extern "C" void kernel_launch(void* const* d_in, const int* in_sizes, int n_in,
                              void* d_out, int out_size, void* d_ws, size_t ws_size,
                              hipStream_t stream) {
    const float* P[19];
    for (int i = 0; i < 19 && i < n_in; i++) P[i] = (const float*)d_in[i];

    const float *x_in, *W1[3], *B1[3], *W2[3], *B2[3], *W3[3], *B3[3];
    x_in = P[0];
    bool dict_order = (in_sizes[2] == 448 * 32);
    if (dict_order) {
        W1[0] = P[1];  B1[0] = P[2];  W1[1] = P[3];  B1[1] = P[4];  W1[2] = P[5];  B1[2] = P[6];
        W2[0] = P[7];  B2[0] = P[8];  W2[1] = P[9];  B2[1] = P[10]; W2[2] = P[11]; B2[2] = P[12];
        W3[0] = P[13]; B3[0] = P[14]; W3[1] = P[15]; B3[1] = P[16]; W3[2] = P[17]; B3[2] = P[18];
    } else {
        W1[0] = P[1];  W1[1] = P[2];  W1[2] = P[3];  B1[0] = P[4];  B1[1] = P[5];  B1[2] = P[6];
        W2[0] = P[7];  W2[1] = P[8];  W2[2] = P[9];  B2[0] = P[10]; B2[1] = P[11]; B2[2] = P[12];
        W3[0] = P[13]; W3[1] = P[14]; W3[2] = P[15]; B3[0] = P[16]; B3[1] = P[17]; B3[2] = P[18];
    }

    float* out = (float*)d_out;
    hipLaunchKernelGGL(cls3_kernel, dim3(2 * HH), dim3(128), 0, stream,
                       x_in,
                       W1[0], B1[0], W1[1], B1[1], W1[2], B1[2],
                       W2[0], B2[0], W2[1], B2[1], W2[2], B2[2],
                       W3[0], B3[0], W3[1], B3[1], W3[2], B3[2],
                       out);
}

// Round 7
// 202.974 us; speedup vs baseline: 2.0594x; 2.0594x over previous
//
#include <hip/hip_runtime.h>

#define HH 448
#define WW 512
#define NPIX (HH * WW)

struct Res { int idx; float ent; };

__device__ __forceinline__ float lrelu(float v) { return v > 0.0f ? v : 0.01f * v; }

__device__ __forceinline__ Res argmax_ent16(const float* __restrict__ v) {
    float m = v[0]; int idx = 0;
#pragma unroll
    for (int i = 1; i < 16; i++) { if (v[i] > m) { m = v[i]; idx = i; } }
    float s = 0.0f, dot = 0.0f;
#pragma unroll
    for (int i = 0; i < 16; i++) {
        float t = __expf(v[i] - m);
        s += t;
        dot = fmaf(t, v[i], dot);
    }
    Res r; r.idx = idx; r.ent = m + __logf(s) - dot / s;
    return r;
}

// y[o] = b[o] + sum_i x[i] * w[i*OUT + o]   (per-lane global weights, layout [in][out])
// Rows processed in pairs: both rows' loads issued before their fmas (deeper VMEM window).
// Per-pixel fma order identical to the single-row version (bitwise-stable).
template <int OUT>
__device__ __forceinline__ void layer_g(const float* __restrict__ wmat,
                                        const float* __restrict__ bias,
                                        const float* __restrict__ x,
                                        float* __restrict__ y) {
    constexpr int NQ = OUT / 4;
    float acc[OUT];
#pragma unroll
    for (int o = 0; o < OUT; o++) acc[o] = bias[o];
    const float4* rows = (const float4*)wmat;
#pragma unroll
    for (int i = 0; i < 32; i += 2) {
        float4 wa[NQ], wb[NQ];
#pragma unroll
        for (int q = 0; q < NQ; q++) wa[q] = rows[i * NQ + q];
#pragma unroll
        for (int q = 0; q < NQ; q++) wb[q] = rows[(i + 1) * NQ + q];
        float xa = x[i];
        float xc = x[i + 1];
#pragma unroll
        for (int q = 0; q < NQ; q++) {
            acc[4 * q + 0] = fmaf(xa, wa[q].x, acc[4 * q + 0]);
            acc[4 * q + 1] = fmaf(xa, wa[q].y, acc[4 * q + 1]);
            acc[4 * q + 2] = fmaf(xa, wa[q].z, acc[4 * q + 2]);
            acc[4 * q + 3] = fmaf(xa, wa[q].w, acc[4 * q + 3]);
        }
#pragma unroll
        for (int q = 0; q < NQ; q++) {
            acc[4 * q + 0] = fmaf(xc, wb[q].x, acc[4 * q + 0]);
            acc[4 * q + 1] = fmaf(xc, wb[q].y, acc[4 * q + 1]);
            acc[4 * q + 2] = fmaf(xc, wb[q].z, acc[4 * q + 2]);
            acc[4 * q + 3] = fmaf(xc, wb[q].w, acc[4 * q + 3]);
        }
    }
#pragma unroll
    for (int o = 0; o < OUT; o++) y[o] = acc[o];
}

// layer with weight layout [OUT][32] ([out][in]); uniform addresses -> L1/scalar broadcast
template <int OUT>
__device__ __forceinline__ void layer_oi(const float* __restrict__ w,
                                         const float* __restrict__ b,
                                         const float* __restrict__ x,
                                         float* __restrict__ y) {
#pragma unroll
    for (int o = 0; o < OUT; o++) {
        const float4* row = (const float4*)(w + o * 32);
        float a = b[o];
#pragma unroll
        for (int q = 0; q < 8; q++) {
            float4 wv = row[q];
            a = fmaf(wv.x, x[4 * q + 0], a);
            a = fmaf(wv.y, x[4 * q + 1], a);
            a = fmaf(wv.z, x[4 * q + 2], a);
            a = fmaf(wv.w, x[4 * q + 3], a);
        }
        y[o] = a;
    }
}

// full expert MLP 32->32->32->16 with per-lane global weights ([in][out] layout)
__device__ __forceinline__ Res expert_mlp_g(const float* __restrict__ xb, int p,
                                            const float* __restrict__ w0, const float* __restrict__ b0,
                                            const float* __restrict__ w1, const float* __restrict__ b1,
                                            const float* __restrict__ w2, const float* __restrict__ b2,
                                            size_t e) {
    float x[32], y[32];
#pragma unroll
    for (int c = 0; c < 32; c++) x[c] = xb[(size_t)c * NPIX + p];
    layer_g<32>(w0 + e * 1024, b0 + e * 32, x, y);
#pragma unroll
    for (int o = 0; o < 32; o++) y[o] = lrelu(y[o]);
    layer_g<32>(w1 + e * 1024, b1 + e * 32, y, x);
#pragma unroll
    for (int o = 0; o < 32; o++) x[o] = lrelu(x[o]);
    float z[16];
    layer_g<16>(w2 + e * 512, b2 + e * 16, x, z);
    return argmax_ent16(z);
}

__global__ __launch_bounds__(256, 2) void cls3_kernel(
    const float* __restrict__ x_in,
    const float* __restrict__ w1_0, const float* __restrict__ b1_0,
    const float* __restrict__ w1_1, const float* __restrict__ b1_1,
    const float* __restrict__ w1_2, const float* __restrict__ b1_2,
    const float* __restrict__ w2_0, const float* __restrict__ b2_0,
    const float* __restrict__ w2_1, const float* __restrict__ b2_1,
    const float* __restrict__ w2_2, const float* __restrict__ b2_2,
    const float* __restrict__ w3_0, const float* __restrict__ b3_0,
    const float* __restrict__ w3_1, const float* __restrict__ b3_1,
    const float* __restrict__ w3_2, const float* __restrict__ b3_2,
    float* __restrict__ out) {
    __shared__ int sCls[256];
    __shared__ int sRaw[256];
    __shared__ int sPerm[256];
    __shared__ int sCnt[192];
    __shared__ int sScan[192];
    __shared__ int sOffs[192];

    const int h = blockIdx.x >> 1;
    const int base = (blockIdx.x & 1) << 8;   // 0 or 256 within the line
    const int t = threadIdx.x;
    const size_t rowoff = (size_t)h * WW + base;

    // ---- stage 1: per-line weights, wave-uniform global reads ----
    {
        float x[32], a[32], bb[32], z[16];
#pragma unroll
        for (int c = 0; c < 32; c++) x[c] = x_in[(size_t)c * NPIX + rowoff + t];
        layer_oi<32>(w1_0 + (size_t)h * 1024, b1_0 + (size_t)h * 32, x, a);
#pragma unroll
        for (int o = 0; o < 32; o++) a[o] = lrelu(a[o]);
        layer_oi<32>(w1_1 + (size_t)h * 1024, b1_1 + (size_t)h * 32, a, bb);
#pragma unroll
        for (int o = 0; o < 32; o++) bb[o] = lrelu(bb[o]);
        layer_oi<16>(w1_2 + (size_t)h * 512, b1_2 + (size_t)h * 16, bb, z);
        Res r = argmax_ent16(z);
        out[NPIX + rowoff + t] = r.ent;  // e1
        sCls[t] = r.idx;                 // inds1 in [0,16)
    }
    if (t < 16) sCnt[t] = 0;
    __syncthreads();

    // ---- counting sort by inds1 (16 bins, 256 pixels) ----
    int rank = atomicAdd(&sCnt[sCls[t]], 1);
    __syncthreads();
    if (t < 16) {
        int v = sCnt[t];
        int incl = v;
#pragma unroll
        for (int d = 1; d < 16; d <<= 1) {
            int n = __shfl_up(incl, d, 64);
            if (t >= d) incl += n;
        }
        sOffs[t] = incl - v;
    }
    __syncthreads();
    sPerm[sOffs[sCls[t]] + rank] = t;
    __syncthreads();

    // ---- stage 2: sorted order, per-lane weight loads (L1 broadcast within runs) ----
    {
        int p = sPerm[t];
        int c1 = sCls[p];
        size_t e = (size_t)h * 16 + c1;
        Res r = expert_mlp_g(x_in + (size_t)32 * NPIX + rowoff, p,
                             w2_0, b2_0, w2_1, b2_1, w2_2, b2_2, e);
        out[2 * NPIX + rowoff + p] = r.ent;  // e2
        int raw = c1 * 12 + r.idx - 2;       // inds12 (unclipped)
        sRaw[p] = raw;
        int cl = raw < 0 ? 0 : (raw > 191 ? 191 : raw);
        sCls[p] = cl;  // own slot only (sPerm is a permutation) -> no race
    }
    if (t < 192) sCnt[t] = 0;
    __syncthreads();

    // ---- counting sort by clipped inds12 (192 bins, 256 pixels) ----
    rank = atomicAdd(&sCnt[sCls[t]], 1);
    __syncthreads();
    if (t < 192) {
        int v = sCnt[t];
        int incl = v;
#pragma unroll
        for (int d = 1; d < 64; d <<= 1) {
            int n = __shfl_up(incl, d, 64);
            if ((t & 63) >= d) incl += n;
        }
        sScan[t] = incl;
    }
    __syncthreads();
    if (t < 192) {
        int add = 0;
        if (t >= 64) add += sScan[63];
        if (t >= 128) add += sScan[127];
        sOffs[t] = sScan[t] + add - sCnt[t];
    }
    __syncthreads();
    sPerm[sOffs[sCls[t]] + rank] = t;
    __syncthreads();

    // ---- stage 3 ----
    {
        int p = sPerm[t];
        int cl = sCls[p];
        int raw = sRaw[p];
        size_t e = (size_t)h * 192 + cl;
        Res r = expert_mlp_g(x_in + (size_t)64 * NPIX + rowoff, p,
                             w3_0, b3_0, w3_1, b3_1, w3_2, b3_2, e);
        out[3 * NPIX + rowoff + p] = r.ent;  // e3
        int i123 = raw * 8 + r.idx - 4;
        i123 = i123 < 0 ? 0 : (i123 > 1535 ? 1535 : i123);
        out[rowoff + p] = (float)i123;       // inds123 as float
    }
}

extern "C" void kernel_launch(void* const* d_in, const int* in_sizes, int n_in,
                              void* d_out, int out_size, void* d_ws, size_t ws_size,
                              hipStream_t stream) {
    const float* P[19];
    for (int i = 0; i < 19 && i < n_in; i++) P[i] = (const float*)d_in[i];

    const float *x_in, *W1[3], *B1[3], *W2[3], *B2[3], *W3[3], *B3[3];
    x_in = P[0];
    bool dict_order = (in_sizes[2] == 448 * 32);
    if (dict_order) {
        W1[0] = P[1];  B1[0] = P[2];  W1[1] = P[3];  B1[1] = P[4];  W1[2] = P[5];  B1[2] = P[6];
        W2[0] = P[7];  B2[0] = P[8];  W2[1] = P[9];  B2[1] = P[10]; W2[2] = P[11]; B2[2] = P[12];
        W3[0] = P[13]; B3[0] = P[14]; W3[1] = P[15]; B3[1] = P[16]; W3[2] = P[17]; B3[2] = P[18];
    } else {
        W1[0] = P[1];  W1[1] = P[2];  W1[2] = P[3];  B1[0] = P[4];  B1[1] = P[5];  B1[2] = P[6];
        W2[0] = P[7];  W2[1] = P[8];  W2[2] = P[9];  B2[0] = P[10]; B2[1] = P[11]; B2[2] = P[12];
        W3[0] = P[13]; W3[1] = P[14]; W3[2] = P[15]; B3[0] = P[16]; B3[1] = P[17]; B3[2] = P[18];
    }

    float* out = (float*)d_out;
    hipLaunchKernelGGL(cls3_kernel, dim3(2 * HH), dim3(256), 0, stream,
                       x_in,
                       W1[0], B1[0], W1[1], B1[1], W1[2], B1[2],
                       W2[0], B2[0], W2[1], B2[1], W2[2], B2[2],
                       W3[0], B3[0], W3[1], B3[1], W3[2], B3[2],
                       out);
}